// Round 3
// baseline (22.617 us; speedup 1.0000x reference)
//
#include <hip/hip_runtime.h>
#include <hip/hip_bf16.h>
#include <stdint.h>
#include <math.h>

// Nucleus sampling reduces to row-wise max+argmax:
// the top-p filter never removes the row max (mask is shifted right by one,
// so the first sorted element always survives; stable argsort preserves
// first-occurrence on ties). So output = (argmax(logits,-1), max(logits,-1)).
//
// Output buffer layout (read back as float32 by the harness):
//   d_out[0 .. S-1]   = tokens (exact integer values stored as float)
//   d_out[S .. 2S-1]  = scores (float)
//
// Perf notes (R2): 512x512 launch = 16 waves/CU (half occupancy) and one
// outstanding dwordx4/wave measured 22 us (4.7 TB/s). This version: 1024
// threads/block (32 waves/CU) + 2-way unroll with independent compare
// chains for 2 loads in flight per wave -> target ~16 us (HBM roofline).

#define BLOCK 1024

__global__ __launch_bounds__(BLOCK) void rowmax_argmax_kernel(
    const float* __restrict__ logits, float* __restrict__ out, int S, int V) {
    const int row = blockIdx.x;
    const float* rp = logits + (size_t)row * (size_t)V;

    // Alignment peel: number of leading elements until 16B-aligned.
    int head = (int)(((16u - ((uintptr_t)rp & 15u)) & 15u) >> 2);
    if (head > V) head = V;
    const int nvec = (V - head) >> 2;
    const int tail_start = head + (nvec << 2);
    const int ntail = V - tail_start;

    const int tid = threadIdx.x;

    // Two independent (val, idx) chains -> 2 loads in flight, shorter
    // dependent compare chains. Each chain visits strictly increasing
    // indices, so strict '>' preserves first occurrence within a chain.
    float best0 = -INFINITY, best1 = -INFINITY;
    int bidx0 = 0x7fffffff, bidx1 = 0x7fffffff;

    // Head (indices 0..head-1, smallest indices — feed chain 0 first).
    if (tid < head) {
        best0 = rp[tid];
        bidx0 = tid;
    }

    const float4* __restrict__ vp = (const float4*)(rp + head);
    int i = tid;
    for (; i + BLOCK < nvec; i += 2 * BLOCK) {
        const float4 a = vp[i];
        const float4 b = vp[i + BLOCK];
        const int ba = head + (i << 2);
        const int bb = head + ((i + BLOCK) << 2);
        if (a.x > best0) { best0 = a.x; bidx0 = ba; }
        if (a.y > best0) { best0 = a.y; bidx0 = ba + 1; }
        if (a.z > best0) { best0 = a.z; bidx0 = ba + 2; }
        if (a.w > best0) { best0 = a.w; bidx0 = ba + 3; }
        if (b.x > best1) { best1 = b.x; bidx1 = bb; }
        if (b.y > best1) { best1 = b.y; bidx1 = bb + 1; }
        if (b.z > best1) { best1 = b.z; bidx1 = bb + 2; }
        if (b.w > best1) { best1 = b.w; bidx1 = bb + 3; }
    }
    if (i < nvec) {
        const float4 a = vp[i];
        const int ba = head + (i << 2);
        if (a.x > best0) { best0 = a.x; bidx0 = ba; }
        if (a.y > best0) { best0 = a.y; bidx0 = ba + 1; }
        if (a.z > best0) { best0 = a.z; bidx0 = ba + 2; }
        if (a.w > best0) { best0 = a.w; bidx0 = ba + 3; }
    }

    // Tail (largest indices, processed last — strict '>' keeps earlier).
    if (tid < ntail) {
        const float v = rp[tail_start + tid];
        if (v > best0) { best0 = v; bidx0 = tail_start + tid; }
    }

    // Merge the two chains: greater val, or equal val with lower index.
    float best = best0;
    int bidx = bidx0;
    if (best1 > best || (best1 == best && bidx1 < bidx)) { best = best1; bidx = bidx1; }

    // Wave (64-lane) reduction.
    #pragma unroll
    for (int off = 32; off >= 1; off >>= 1) {
        const float ov = __shfl_down(best, off, 64);
        const int   oi = __shfl_down(bidx, off, 64);
        if (ov > best || (ov == best && oi < bidx)) { best = ov; bidx = oi; }
    }

    // Cross-wave reduction via LDS (BLOCK/64 waves).
    __shared__ float s_val[BLOCK / 64];
    __shared__ int   s_idx[BLOCK / 64];
    const int wave = tid >> 6;
    const int lane = tid & 63;
    if (lane == 0) { s_val[wave] = best; s_idx[wave] = bidx; }
    __syncthreads();

    if (tid == 0) {
        float fb = s_val[0];
        int fi = s_idx[0];
        #pragma unroll
        for (int w = 1; w < BLOCK / 64; ++w) {
            const float ov = s_val[w];
            const int   oi = s_idx[w];
            if (ov > fb || (ov == fb && oi < fi)) { fb = ov; fi = oi; }
        }
        out[row]     = (float)fi;  // token index, exactly representable (< 2^24)
        out[S + row] = fb;         // score
    }
}

extern "C" void kernel_launch(void* const* d_in, const int* in_sizes, int n_in,
                              void* d_out, int out_size, void* d_ws, size_t ws_size,
                              hipStream_t stream) {
    const float* logits = (const float*)d_in[0];
    float* out = (float*)d_out;

    const int S = out_size / 2;              // 512 rows (tokens + scores)
    const int V = in_sizes[0] / S;           // 50257 vocab

    rowmax_argmax_kernel<<<S, BLOCK, 0, stream>>>(logits, out, S, V);
}